// Round 4
// baseline (190.956 us; speedup 1.0000x reference)
//
#include <hip/hip_runtime.h>

#define B_ 64
#define N_ 64
#define D_ 256
#define LAP_ 16
#define M_ 2016           // 64*63/2
#define TOK_ 2081         // 1 + 64 + 2016

typedef float f32x4 __attribute__((ext_vector_type(4)));

__device__ __forceinline__ void nt_store4(float* p, float4 v) {
    f32x4 vv = {v.x, v.y, v.z, v.w};
    __builtin_nontemporal_store(vv, (f32x4*)p);
}

// ---------------------------------------------------------------------------
// Kernel 1: stable compaction. One block per batch, 256 threads, 8 edges/thread.
// pack[b*M + p] = i | (j<<8) | (valid<<16)
// ---------------------------------------------------------------------------
__global__ __launch_bounds__(256) void compact_kernel(const int* __restrict__ adj,
                                                      int* __restrict__ pack) {
    int b = blockIdx.x;
    int t = threadIdx.x;
    __shared__ int s[256];
    __shared__ int s_total;

    int ii[8], jj[8], vv[8];
    int c = 0;
#pragma unroll
    for (int k = 0; k < 8; k++) {
        int m = t * 8 + k;
        int valid = 0, i = 0, j = 0;
        if (m < M_) {
            // row i: off(i) = (127*i - i*i)/2, find largest i with off(i) <= m
            float fm = (float)m;
            int gi = (int)((127.0f - sqrtf(127.0f * 127.0f - 8.0f * fm)) * 0.5f);
            if (gi < 0) gi = 0;
            if (gi > 62) gi = 62;
            while (gi > 0 && (127 * gi - gi * gi) / 2 > m) gi--;
            while (gi < 62 && (127 * (gi + 1) - (gi + 1) * (gi + 1)) / 2 <= m) gi++;
            i = gi;
            j = i + 1 + (m - (127 * i - i * i) / 2);
            valid = (adj[b * (N_ * N_) + i * N_ + j] > 0) ? 1 : 0;
        }
        ii[k] = i; jj[k] = j; vv[k] = valid;
        c += valid;
    }
    s[t] = c;
    __syncthreads();
    // inclusive Hillis-Steele scan over 256 thread-counts
    for (int off = 1; off < 256; off <<= 1) {
        int v = (t >= off) ? s[t - off] : 0;
        __syncthreads();
        s[t] += v;
        __syncthreads();
    }
    if (t == 255) s_total = s[255];
    __syncthreads();
    int total = s_total;
    int run = s[t] - c;  // exclusive prefix: #valid with index < t*8
#pragma unroll
    for (int k = 0; k < 8; k++) {
        int m = t * 8 + k;
        if (m < M_) {
            int p;
            if (vv[k]) { p = run; run++; }
            else       { p = total + (m - run); }
            pack[b * M_ + p] = ii[k] | (jj[k] << 8) | (vv[k] << 16);
        }
    }
}

// ---------------------------------------------------------------------------
// Kernel 2 (fused): edge tokens + node tokens + graph token + pad_mask.
// Grid (B, 22), 256 threads.
//   blockIdx.y < 21 : 96 edge tokens (24 per wave). Weights register-resident
//                     (lane owns 4 cols: 33 float4 = 132 VGPR), token loop NOT
//                     unrolled to keep live set < 256 VGPR (no scratch).
//   blockIdx.y == 21: node tokens (16/wave) + graph token + mask head.
// eigvec for the batch staged once in LDS (4 KB) and reused by both paths.
// ---------------------------------------------------------------------------
__global__ __launch_bounds__(256) void fused_kernel(const float* __restrict__ node_feats,
                                                    const float* __restrict__ eigvec,
                                                    const float* __restrict__ W_lap,
                                                    const float* __restrict__ W_edge,
                                                    const float* __restrict__ b_edge,
                                                    const float* __restrict__ type_embed,
                                                    const float* __restrict__ graph_tok,
                                                    const int* __restrict__ pack,
                                                    float* __restrict__ out) {
    __shared__ float sEig[N_ * LAP_]; // 4 KB
    int b = blockIdx.x;
    int t = threadIdx.x;
    int wave = t >> 6, lane = t & 63;

    ((float4*)sEig)[t] = ((const float4*)(eigvec + (size_t)b * N_ * LAP_))[t];
    __syncthreads();

    if (blockIdx.y == 21) {
        // ---- node tokens ----
        float* outb = out + (size_t)b * TOK_ * D_;
#pragma unroll 1
        for (int q = 0; q < 16; q++) {
            int n = wave * 16 + q;
            const float* e = sEig + n * LAP_;
            float4 acc = ((const float4*)(node_feats + ((size_t)b * N_ + n) * D_))[lane];
#pragma unroll
            for (int l = 0; l < LAP_; l++) {
                float el = e[l];
                float4 w = ((const float4*)(W_lap + l * D_))[lane];
                acc.x += el * w.x; acc.y += el * w.y;
                acc.z += el * w.z; acc.w += el * w.w;
            }
            nt_store4(outb + (size_t)(1 + n) * D_ + lane * 4, acc);
        }
        // ---- graph token + mask head ----
        outb[t] = graph_tok[t];
        float* mask = out + (size_t)B_ * TOK_ * D_;
        if (t < 1 + N_) mask[b * TOK_ + t] = 0.0f;
        return;
    }

    // ---- edge tokens ----
    float4 base = ((const float4*)W_edge)[lane];
    {
        float4 bb = ((const float4*)b_edge)[lane];
        float4 te = ((const float4*)(type_embed + D_))[lane];
        base.x += bb.x + te.x; base.y += bb.y + te.y;
        base.z += bb.z + te.z; base.w += bb.w + te.w;
    }
    float4 w1[LAP_], w2[LAP_];
#pragma unroll
    for (int l = 0; l < LAP_; l++) {
        w1[l] = ((const float4*)(W_edge + (1 + l) * D_))[lane];
        w2[l] = ((const float4*)(W_edge + (1 + LAP_ + l) * D_))[lane];
    }

    float* maskb = out + (size_t)B_ * TOK_ * D_ + (size_t)b * TOK_ + 1 + N_;
    float* outb = out + (size_t)b * TOK_ * D_ + (size_t)(1 + N_) * D_;
    int p0 = blockIdx.y * 96 + wave * 24;

#pragma unroll 1
    for (int k = 0; k < 24; k++) {
        int p = p0 + k;
        int pk = pack[b * M_ + p];
        int valid = (pk >> 16) & 1;
        float4 acc = make_float4(0.f, 0.f, 0.f, 0.f);
        if (valid) {
            int si = pk & 0xff, di = (pk >> 8) & 0xff;
            const float* eu = sEig + si * LAP_;
            const float* ev = sEig + di * LAP_;
            acc = base;
#pragma unroll
            for (int l = 0; l < LAP_; l++) {
                float pu = eu[l], pv = ev[l];
                acc.x += pu * w1[l].x + pv * w2[l].x;
                acc.y += pu * w1[l].y + pv * w2[l].y;
                acc.z += pu * w1[l].z + pv * w2[l].z;
                acc.w += pu * w1[l].w + pv * w2[l].w;
            }
        }
        nt_store4(outb + (size_t)p * D_ + lane * 4, acc);
        if (lane == 0) maskb[p] = valid ? 0.0f : 1.0f;
    }
}

extern "C" void kernel_launch(void* const* d_in, const int* in_sizes, int n_in,
                              void* d_out, int out_size, void* d_ws, size_t ws_size,
                              hipStream_t stream) {
    const int*   adj        = (const int*)d_in[0];
    const float* node_feats = (const float*)d_in[1];
    const float* eigvec     = (const float*)d_in[2];
    const float* W_lap      = (const float*)d_in[3];
    const float* W_edge     = (const float*)d_in[4];
    const float* b_edge     = (const float*)d_in[5];
    const float* type_embed = (const float*)d_in[6];
    const float* graph_tok  = (const float*)d_in[7];
    float* out = (float*)d_out;
    int* pack = (int*)d_ws;  // B*M ints = 516 KB

    compact_kernel<<<dim3(B_), dim3(256), 0, stream>>>(adj, pack);
    fused_kernel<<<dim3(B_, 22), dim3(256), 0, stream>>>(node_feats, eigvec, W_lap,
                                                         W_edge, b_edge, type_embed,
                                                         graph_tok, pack, out);
}

// Round 5
// 180.656 us; speedup vs baseline: 1.0570x; 1.0570x over previous
//
#include <hip/hip_runtime.h>

#define B_ 64
#define N_ 64
#define D_ 256
#define LAP_ 16
#define M_ 2016           // 64*63/2
#define TOK_ 2081         // 1 + 64 + 2016

// ---------------------------------------------------------------------------
// Kernel 1: stable compaction. One block per batch, 256 threads, 8 edges/thread.
// pack[b*M + p] = i | (j<<8) | (valid<<16)
// ---------------------------------------------------------------------------
__global__ __launch_bounds__(256) void compact_kernel(const int* __restrict__ adj,
                                                      int* __restrict__ pack) {
    int b = blockIdx.x;
    int t = threadIdx.x;
    __shared__ int s[256];
    __shared__ int s_total;

    int ii[8], jj[8], vv[8];
    int c = 0;
#pragma unroll
    for (int k = 0; k < 8; k++) {
        int m = t * 8 + k;
        int valid = 0, i = 0, j = 0;
        if (m < M_) {
            // row i: off(i) = (127*i - i*i)/2, find largest i with off(i) <= m
            float fm = (float)m;
            int gi = (int)((127.0f - sqrtf(127.0f * 127.0f - 8.0f * fm)) * 0.5f);
            if (gi < 0) gi = 0;
            if (gi > 62) gi = 62;
            while (gi > 0 && (127 * gi - gi * gi) / 2 > m) gi--;
            while (gi < 62 && (127 * (gi + 1) - (gi + 1) * (gi + 1)) / 2 <= m) gi++;
            i = gi;
            j = i + 1 + (m - (127 * i - i * i) / 2);
            valid = (adj[b * (N_ * N_) + i * N_ + j] > 0) ? 1 : 0;
        }
        ii[k] = i; jj[k] = j; vv[k] = valid;
        c += valid;
    }
    s[t] = c;
    __syncthreads();
    // inclusive Hillis-Steele scan over 256 thread-counts
    for (int off = 1; off < 256; off <<= 1) {
        int v = (t >= off) ? s[t - off] : 0;
        __syncthreads();
        s[t] += v;
        __syncthreads();
    }
    if (t == 255) s_total = s[255];
    __syncthreads();
    int total = s_total;
    int run = s[t] - c;  // exclusive prefix: #valid with index < t*8
#pragma unroll
    for (int k = 0; k < 8; k++) {
        int m = t * 8 + k;
        if (m < M_) {
            int p;
            if (vv[k]) { p = run; run++; }
            else       { p = total + (m - run); }
            pack[b * M_ + p] = ii[k] | (jj[k] << 8) | (vv[k] << 16);
        }
    }
}

// ---------------------------------------------------------------------------
// Kernel 2 (fused): edge tokens + node tokens + graph token + pad_mask.
// Grid (B, 22), 256 threads.
//   blockIdx.y < 21 : 96 edge tokens (24 per wave). Weights register-resident
//                     (lane owns 4 cols: 33 float4 = 132 VGPR). Token loop
//                     unrolled x2: 2 tokens in flight (~225 VGPR live, no
//                     spill) so LDS reads of token k+1 overlap FMAs of k.
//                     pack[] staged in LDS: per-token index read is ds_read,
//                     not a 200-cyc L2 round trip.
//   blockIdx.y == 21: node tokens (16/wave) + graph token + mask head.
// ---------------------------------------------------------------------------
__global__ __launch_bounds__(256) void fused_kernel(const float* __restrict__ node_feats,
                                                    const float* __restrict__ eigvec,
                                                    const float* __restrict__ W_lap,
                                                    const float* __restrict__ W_edge,
                                                    const float* __restrict__ b_edge,
                                                    const float* __restrict__ type_embed,
                                                    const float* __restrict__ graph_tok,
                                                    const int* __restrict__ pack,
                                                    float* __restrict__ out) {
    __shared__ float sEig[N_ * LAP_]; // 4 KB
    __shared__ int   sPack[96];
    int b = blockIdx.x;
    int t = threadIdx.x;
    int wave = t >> 6, lane = t & 63;

    ((float4*)sEig)[t] = ((const float4*)(eigvec + (size_t)b * N_ * LAP_))[t];

    if (blockIdx.y == 21) {
        __syncthreads();
        // ---- node tokens ----
        float* outb = out + (size_t)b * TOK_ * D_;
#pragma unroll 2
        for (int q = 0; q < 16; q++) {
            int n = wave * 16 + q;
            const float* e = sEig + n * LAP_;
            float4 acc = ((const float4*)(node_feats + ((size_t)b * N_ + n) * D_))[lane];
#pragma unroll
            for (int l = 0; l < LAP_; l++) {
                float el = e[l];
                float4 w = ((const float4*)(W_lap + l * D_))[lane];
                acc.x += el * w.x; acc.y += el * w.y;
                acc.z += el * w.z; acc.w += el * w.w;
            }
            ((float4*)(outb + (size_t)(1 + n) * D_))[lane] = acc;
        }
        // ---- graph token + mask head ----
        outb[t] = graph_tok[t];
        float* mask = out + (size_t)B_ * TOK_ * D_;
        if (t < 1 + N_) mask[b * TOK_ + t] = 0.0f;
        return;
    }

    if (t < 96) sPack[t] = pack[b * M_ + blockIdx.y * 96 + t];

    // ---- edge tokens: register-resident weights ----
    float4 base = ((const float4*)W_edge)[lane];
    {
        float4 bb = ((const float4*)b_edge)[lane];
        float4 te = ((const float4*)(type_embed + D_))[lane];
        base.x += bb.x + te.x; base.y += bb.y + te.y;
        base.z += bb.z + te.z; base.w += bb.w + te.w;
    }
    float4 w1[LAP_], w2[LAP_];
#pragma unroll
    for (int l = 0; l < LAP_; l++) {
        w1[l] = ((const float4*)(W_edge + (1 + l) * D_))[lane];
        w2[l] = ((const float4*)(W_edge + (1 + LAP_ + l) * D_))[lane];
    }
    __syncthreads();

    float* maskb = out + (size_t)B_ * TOK_ * D_ + (size_t)b * TOK_ + 1 + N_;
    float* outb = out + (size_t)b * TOK_ * D_ + (size_t)(1 + N_) * D_;
    int p0 = blockIdx.y * 96 + wave * 24;

#pragma unroll 2
    for (int k = 0; k < 24; k++) {
        int p = p0 + k;
        int pk = sPack[wave * 24 + k];
        int valid = (pk >> 16) & 1;
        float4 acc = make_float4(0.f, 0.f, 0.f, 0.f);
        if (valid) {
            int si = pk & 0xff, di = (pk >> 8) & 0xff;
            const float* eu = sEig + si * LAP_;
            const float* ev = sEig + di * LAP_;
            acc = base;
#pragma unroll
            for (int l = 0; l < LAP_; l++) {
                float pu = eu[l], pv = ev[l];
                acc.x += pu * w1[l].x + pv * w2[l].x;
                acc.y += pu * w1[l].y + pv * w2[l].y;
                acc.z += pu * w1[l].z + pv * w2[l].z;
                acc.w += pu * w1[l].w + pv * w2[l].w;
            }
        }
        ((float4*)(outb + (size_t)p * D_))[lane] = acc;
        if (lane == 0) maskb[p] = valid ? 0.0f : 1.0f;
    }
}

extern "C" void kernel_launch(void* const* d_in, const int* in_sizes, int n_in,
                              void* d_out, int out_size, void* d_ws, size_t ws_size,
                              hipStream_t stream) {
    const int*   adj        = (const int*)d_in[0];
    const float* node_feats = (const float*)d_in[1];
    const float* eigvec     = (const float*)d_in[2];
    const float* W_lap      = (const float*)d_in[3];
    const float* W_edge     = (const float*)d_in[4];
    const float* b_edge     = (const float*)d_in[5];
    const float* type_embed = (const float*)d_in[6];
    const float* graph_tok  = (const float*)d_in[7];
    float* out = (float*)d_out;
    int* pack = (int*)d_ws;  // B*M ints = 516 KB

    compact_kernel<<<dim3(B_), dim3(256), 0, stream>>>(adj, pack);
    fused_kernel<<<dim3(B_, 22), dim3(256), 0, stream>>>(node_feats, eigvec, W_lap,
                                                         W_edge, b_edge, type_embed,
                                                         graph_tok, pack, out);
}

// Round 6
// 179.595 us; speedup vs baseline: 1.0633x; 1.0059x over previous
//
#include <hip/hip_runtime.h>

#define B_ 64
#define N_ 64
#define D_ 256
#define LAP_ 16
#define M_ 2016           // 64*63/2
#define TOK_ 2081         // 1 + 64 + 2016

// ---------------------------------------------------------------------------
// Kernel 1: stable compaction. One block per batch, 256 threads, 8 edges/thread.
// pack[b*M + p] = i | (j<<8) | (valid<<16)
// Scan: wave-shuffle inclusive scan + 4-wave LDS combine (2 barriers total).
// ---------------------------------------------------------------------------
__global__ __launch_bounds__(256) void compact_kernel(const int* __restrict__ adj,
                                                      int* __restrict__ pack) {
    int b = blockIdx.x;
    int t = threadIdx.x;
    int wave = t >> 6, lane = t & 63;
    __shared__ int sWave[4];

    int ii[8], jj[8], vv[8];
    int c = 0;
#pragma unroll
    for (int k = 0; k < 8; k++) {
        int m = t * 8 + k;
        int valid = 0, i = 0, j = 0;
        if (m < M_) {
            // row i: off(i) = (127*i - i*i)/2, largest i with off(i) <= m
            float fm = (float)m;
            int gi = (int)((127.0f - sqrtf(127.0f * 127.0f - 8.0f * fm)) * 0.5f);
            if (gi < 0) gi = 0;
            if (gi > 62) gi = 62;
            while (gi > 0 && (127 * gi - gi * gi) / 2 > m) gi--;
            while (gi < 62 && (127 * (gi + 1) - (gi + 1) * (gi + 1)) / 2 <= m) gi++;
            i = gi;
            j = i + 1 + (m - (127 * i - i * i) / 2);
            valid = (adj[b * (N_ * N_) + i * N_ + j] > 0) ? 1 : 0;
        }
        ii[k] = i; jj[k] = j; vv[k] = valid;
        c += valid;
    }
    // wave-level inclusive scan of c (no barriers)
    int val = c;
#pragma unroll
    for (int off = 1; off < 64; off <<= 1) {
        int v = __shfl_up(val, off, 64);
        if (lane >= off) val += v;
    }
    if (lane == 63) sWave[wave] = val;
    __syncthreads();
    int w0 = sWave[0], w1 = sWave[1], w2 = sWave[2], w3 = sWave[3];
    int wbase = (wave > 0 ? w0 : 0) + (wave > 1 ? w1 : 0) + (wave > 2 ? w2 : 0);
    int total = w0 + w1 + w2 + w3;
    int run = wbase + val - c;  // exclusive prefix of valid count
#pragma unroll
    for (int k = 0; k < 8; k++) {
        int m = t * 8 + k;
        if (m < M_) {
            int p;
            if (vv[k]) { p = run; run++; }
            else       { p = total + (m - run); }
            pack[b * M_ + p] = ii[k] | (jj[k] << 8) | (vv[k] << 16);
        }
    }
}

// ---------------------------------------------------------------------------
// Kernel 2 (fused): edge tokens + node tokens + graph token + pad_mask.
// Grid (B, 22), 256 threads.
//   blockIdx.y < 21 : 96 edge tokens (24/wave). Weights register-resident
//                     (lane owns 4 cols: 33 float4 = 132 VGPR), unroll 2
//                     (2 tokens in flight, no spill). pack staged via LDS;
//                     pad_mask written coalesced (96 consecutive dwords).
//   blockIdx.y == 21: node tokens (16/wave) + graph token + mask head.
// ---------------------------------------------------------------------------
__global__ __launch_bounds__(256) void fused_kernel(const float* __restrict__ node_feats,
                                                    const float* __restrict__ eigvec,
                                                    const float* __restrict__ W_lap,
                                                    const float* __restrict__ W_edge,
                                                    const float* __restrict__ b_edge,
                                                    const float* __restrict__ type_embed,
                                                    const float* __restrict__ graph_tok,
                                                    const int* __restrict__ pack,
                                                    float* __restrict__ out) {
    __shared__ float sEig[N_ * LAP_]; // 4 KB
    __shared__ int   sPack[96];
    int b = blockIdx.x;
    int t = threadIdx.x;
    int wave = t >> 6, lane = t & 63;

    if (blockIdx.y == 21) {
        ((float4*)sEig)[t] = ((const float4*)(eigvec + (size_t)b * N_ * LAP_))[t];
        __syncthreads();
        // ---- node tokens ----
        float* outb = out + (size_t)b * TOK_ * D_;
#pragma unroll 2
        for (int q = 0; q < 16; q++) {
            int n = wave * 16 + q;
            const float* e = sEig + n * LAP_;
            float4 acc = ((const float4*)(node_feats + ((size_t)b * N_ + n) * D_))[lane];
#pragma unroll
            for (int l = 0; l < LAP_; l++) {
                float el = e[l];
                float4 w = ((const float4*)(W_lap + l * D_))[lane];
                acc.x += el * w.x; acc.y += el * w.y;
                acc.z += el * w.z; acc.w += el * w.w;
            }
            ((float4*)(outb + (size_t)(1 + n) * D_))[lane] = acc;
        }
        // ---- graph token + mask head ----
        outb[t] = graph_tok[t];
        float* mask = out + (size_t)B_ * TOK_ * D_;
        if (t < 1 + N_) mask[b * TOK_ + t] = 0.0f;
        return;
    }

    // ---- edge path ----
    // issue pack load first (hides L2 latency behind weight loads), write
    // pad_mask coalesced while staging
    float* maskb = out + (size_t)B_ * TOK_ * D_ + (size_t)b * TOK_ + 1 + N_;
    if (t < 96) {
        int pkv = pack[b * M_ + blockIdx.y * 96 + t];
        sPack[t] = pkv;
        maskb[blockIdx.y * 96 + t] = ((pkv >> 16) & 1) ? 0.0f : 1.0f;
    }
    ((float4*)sEig)[t] = ((const float4*)(eigvec + (size_t)b * N_ * LAP_))[t];

    // register-resident weights: lane owns columns [4*lane, 4*lane+4)
    float4 base = ((const float4*)W_edge)[lane];
    {
        float4 bb = ((const float4*)b_edge)[lane];
        float4 te = ((const float4*)(type_embed + D_))[lane];
        base.x += bb.x + te.x; base.y += bb.y + te.y;
        base.z += bb.z + te.z; base.w += bb.w + te.w;
    }
    float4 w1[LAP_], w2[LAP_];
#pragma unroll
    for (int l = 0; l < LAP_; l++) {
        w1[l] = ((const float4*)(W_edge + (1 + l) * D_))[lane];
        w2[l] = ((const float4*)(W_edge + (1 + LAP_ + l) * D_))[lane];
    }
    __syncthreads();

    float* outb = out + (size_t)b * TOK_ * D_ + (size_t)(1 + N_) * D_;
    int p0 = blockIdx.y * 96 + wave * 24;

#pragma unroll 2
    for (int k = 0; k < 24; k++) {
        int p = p0 + k;
        int pk = sPack[wave * 24 + k];
        int valid = (pk >> 16) & 1;
        float4 acc = make_float4(0.f, 0.f, 0.f, 0.f);
        if (valid) {
            int si = pk & 0xff, di = (pk >> 8) & 0xff;
            const float4* eu4 = (const float4*)(sEig + si * LAP_);
            const float4* ev4 = (const float4*)(sEig + di * LAP_);
            float4 eu[4], ev[4];
#pragma unroll
            for (int q = 0; q < 4; q++) { eu[q] = eu4[q]; ev[q] = ev4[q]; }
            const float* euf = (const float*)eu;
            const float* evf = (const float*)ev;
            acc = base;
#pragma unroll
            for (int l = 0; l < LAP_; l++) {
                float pu = euf[l], pv = evf[l];
                acc.x += pu * w1[l].x + pv * w2[l].x;
                acc.y += pu * w1[l].y + pv * w2[l].y;
                acc.z += pu * w1[l].z + pv * w2[l].z;
                acc.w += pu * w1[l].w + pv * w2[l].w;
            }
        }
        ((float4*)(outb + (size_t)p * D_))[lane] = acc;
    }
}

extern "C" void kernel_launch(void* const* d_in, const int* in_sizes, int n_in,
                              void* d_out, int out_size, void* d_ws, size_t ws_size,
                              hipStream_t stream) {
    const int*   adj        = (const int*)d_in[0];
    const float* node_feats = (const float*)d_in[1];
    const float* eigvec     = (const float*)d_in[2];
    const float* W_lap      = (const float*)d_in[3];
    const float* W_edge     = (const float*)d_in[4];
    const float* b_edge     = (const float*)d_in[5];
    const float* type_embed = (const float*)d_in[6];
    const float* graph_tok  = (const float*)d_in[7];
    float* out = (float*)d_out;
    int* pack = (int*)d_ws;  // B*M ints = 516 KB

    compact_kernel<<<dim3(B_), dim3(256), 0, stream>>>(adj, pack);
    fused_kernel<<<dim3(B_, 22), dim3(256), 0, stream>>>(node_feats, eigvec, W_lap,
                                                         W_edge, b_edge, type_embed,
                                                         graph_tok, pack, out);
}